// Round 20
// baseline (189.924 us; speedup 1.0000x reference)
//
#include <hip/hip_runtime.h>

using bf16 = __bf16;
typedef bf16 bf16x4 __attribute__((ext_vector_type(4)));
typedef bf16 bf16x8 __attribute__((ext_vector_type(8)));
typedef float f32x4 __attribute__((ext_vector_type(4)));

// ---------------------------------------------------------------- helpers
// GEMM LDS tiles: row stride 192 bf16 (384B, bank-aligned). XOR row&7 into
// element bits [3:5] -> 8 distinct 16B slots per 8 rows.
__device__ __forceinline__ int swz192(int row, int col) {
  return row * 192 + (col ^ ((row & 7) << 3));
}
// attention k tile: 256 rows x 32 bf16 (64B rows). Pack 2 rows per 128B block,
// XOR (row>>1)&3 into col bits [3:4]. Linear element index for (row, chunk)
// without the XOR is (row>>1)*64 + (row&1)*32 + chunk*8 — used by the r20
// global_load_lds staging (XOR moved to the global source column, rule #21).
__device__ __forceinline__ int qk_idx(int row, int col) {
  return (row >> 1) * 64 + (row & 1) * 32 + (col ^ (((row >> 1) & 3) << 3));
}
// V^T tile: 32 rows(d) x 256 bf16. Rotate n by 16*(d>>3); XOR (d&7)<<3
// (bank conflicts 3.5M -> 0.96M measured in r4). SCALAR writes only —
// r13's packed-b32 variant FAILED correctness; do not retry (ledger).
__device__ __forceinline__ int vt_idx(int d, int n) {
  return d * 256 + (((n + ((d >> 3) << 4)) & 255) ^ ((d & 7) << 3));
}
// P tile (per wave): 16 rows x 64 bf16 (K=64 quarter) -> XOR r&7 into 16B slots.
__device__ __forceinline__ int p_idx4(int wv, int r, int c) {
  return wv * 1024 + r * 64 + (c ^ ((r & 7) << 3));
}

#define LOG2E 1.44269504088896f
#define GLOAD_LDS(src, dst)                                                     \
  __builtin_amdgcn_global_load_lds(                                             \
      (const __attribute__((address_space(1))) void*)(src),                     \
      (__attribute__((address_space(3))) void*)(dst), 16, 0, 0)

// ---------------------------------------------------------------- QKV GEMM + cpbT
// r19 version verbatim: cpbT range-merged into the QKV GEMM dispatch.
// blocks <9216: r11 GEMM (BM=BN=64, gload_lds staging, pre-swizzled source,
// XCD-co-locating swizzle, q/k normalize + scale folding). >=9216: cpbT.
__global__ __launch_bounds__(256) void k_qkv(const bf16* __restrict__ A,
                                             const bf16* __restrict__ W,
                                             const float* __restrict__ bias,
                                             const float* __restrict__ lsc,
                                             bf16* __restrict__ Op,
                                             const float* __restrict__ bt,
                                             const int* __restrict__ rel,
                                             float* __restrict__ biasfT) {
  __shared__ bf16 As[64 * 192];
  __shared__ bf16 Bs[64 * 192];
  const int bid = blockIdx.x;
  const int t = threadIdx.x;

  if (bid >= 9216) {  // ---- cpbT: biasfT[h][j][i] = l2e*16*sig(bt[rel[i][j]][h])
    const int idx = (bid - 9216) * 256 + t;  // 6*65536 exactly
    const int hh = idx >> 16;
    const int jj = (idx >> 8) & 255;
    const int i = idx & 255;
    const float v = bt[rel[i * 256 + jj] * 6 + hh];
    biasfT[idx] = LOG2E * 16.f / (1.f + __builtin_amdgcn_exp2f(-LOG2E * v));
    return;
  }

  const int xcd = bid & 7;
  const int j = bid >> 3;
  const int m0 = (xcd + 8 * (j / 9)) * 64;
  const int n0 = (j % 9) * 64;

#pragma unroll
  for (int i = 0; i < 6; ++i) {
    const int f = t + i * 256;
    const int row = f / 24, c8 = f % 24;
    const int csw = (c8 ^ (row & 7)) * 8;  // pre-swizzled source chunk
    GLOAD_LDS(&A[(m0 + row) * 192 + csw], &As[f * 8]);
    GLOAD_LDS(&W[(n0 + row) * 192 + csw], &Bs[f * 8]);
  }
  __syncthreads();

  const int w = t >> 6, lane = t & 63, lo = lane & 15, hi = lane >> 4;
  const int wm = (w >> 1) * 32, wn = (w & 1) * 32;
  f32x4 acc[2][2];
#pragma unroll
  for (int a = 0; a < 2; ++a)
#pragma unroll
    for (int c = 0; c < 2; ++c) acc[a][c] = f32x4{0.f, 0.f, 0.f, 0.f};

#pragma unroll
  for (int ks = 0; ks < 6; ++ks) {
    const int k0 = ks * 32 + hi * 8;
    bf16x8 af[2], bfr[2];
#pragma unroll
    for (int ri = 0; ri < 2; ++ri)
      af[ri] = *reinterpret_cast<const bf16x8*>(&As[swz192(wm + ri * 16 + lo, k0)]);
#pragma unroll
    for (int ci = 0; ci < 2; ++ci)
      bfr[ci] = *reinterpret_cast<const bf16x8*>(&Bs[swz192(wn + ci * 16 + lo, k0)]);
#pragma unroll
    for (int ri = 0; ri < 2; ++ri)
#pragma unroll
      for (int ci = 0; ci < 2; ++ci)
        acc[ri][ci] = __builtin_amdgcn_mfma_f32_16x16x32_bf16(af[ri], bfr[ci], acc[ri][ci], 0, 0, 0);
  }

  const int cb = n0 + wn;           // wave's 32-col block start (one head group)
  const bool donorm = (cb < 384);   // q or k
  float smul = 1.f;
  if (cb < 192)                     // q: fold logit scale AND log2e (exp->exp2)
    smul = expf(fminf(lsc[cb >> 5], 4.605170185988091f)) * LOG2E;
  const int col0 = cb + lo;
  const float b0 = bias[col0], b1 = bias[col0 + 16];
#pragma unroll
  for (int ri = 0; ri < 2; ++ri)
#pragma unroll
    for (int rr = 0; rr < 4; ++rr) {
      float v0 = acc[ri][0][rr] + b0;
      float v1 = acc[ri][1][rr] + b1;
      if (donorm) {
        float ss = v0 * v0 + v1 * v1;
        ss += __shfl_xor(ss, 1, 16);
        ss += __shfl_xor(ss, 2, 16);
        ss += __shfl_xor(ss, 4, 16);
        ss += __shfl_xor(ss, 8, 16);
        const float rn = smul / fmaxf(sqrtf(ss), 1e-12f);
        v0 *= rn;
        v1 *= rn;
      }
      const int row = m0 + wm + ri * 16 + hi * 4 + rr;
      Op[row * 576 + col0] = (bf16)v0;
      Op[row * 576 + col0 + 16] = (bf16)v1;
    }
}

// ---------------------------------------------------------------- proj GEMM
// r11 version verbatim. out f32 nt-stored (never re-read).
template <int NT>
__global__ __launch_bounds__(256) void k_gemm(const bf16* __restrict__ A,
                                              const bf16* __restrict__ W,
                                              const float* __restrict__ bias,
                                              float* __restrict__ Op, int Ntot) {
  __shared__ bf16 As[64 * 192];
  __shared__ bf16 Bs[64 * 192];
  const int bid = blockIdx.x;
  const int xcd = bid & 7;
  const int j = bid >> 3;
  const int m0 = (xcd + 8 * (j / NT)) * 64;
  const int n0 = (j % NT) * 64;
  const int t = threadIdx.x;

#pragma unroll
  for (int i = 0; i < 6; ++i) {
    const int f = t + i * 256;
    const int row = f / 24, c8 = f % 24;
    const int csw = (c8 ^ (row & 7)) * 8;  // pre-swizzled source chunk
    GLOAD_LDS(&A[(m0 + row) * 192 + csw], &As[f * 8]);
    GLOAD_LDS(&W[(n0 + row) * 192 + csw], &Bs[f * 8]);
  }
  __syncthreads();

  const int w = t >> 6, lane = t & 63, lo = lane & 15, hi = lane >> 4;
  const int wm = (w >> 1) * 32, wn = (w & 1) * 32;
  f32x4 acc[2][2];
#pragma unroll
  for (int a = 0; a < 2; ++a)
#pragma unroll
    for (int c = 0; c < 2; ++c) acc[a][c] = f32x4{0.f, 0.f, 0.f, 0.f};

#pragma unroll
  for (int ks = 0; ks < 6; ++ks) {
    const int k0 = ks * 32 + hi * 8;
    bf16x8 af[2], bfr[2];
#pragma unroll
    for (int ri = 0; ri < 2; ++ri)
      af[ri] = *reinterpret_cast<const bf16x8*>(&As[swz192(wm + ri * 16 + lo, k0)]);
#pragma unroll
    for (int ci = 0; ci < 2; ++ci)
      bfr[ci] = *reinterpret_cast<const bf16x8*>(&Bs[swz192(wn + ci * 16 + lo, k0)]);
#pragma unroll
    for (int ri = 0; ri < 2; ++ri)
#pragma unroll
      for (int ci = 0; ci < 2; ++ci)
        acc[ri][ci] = __builtin_amdgcn_mfma_f32_16x16x32_bf16(af[ri], bfr[ci], acc[ri][ci], 0, 0, 0);
  }

#pragma unroll
  for (int ri = 0; ri < 2; ++ri)
#pragma unroll
    for (int ci = 0; ci < 2; ++ci) {
      const int col = n0 + wn + ci * 16 + lo;
      const float bv = bias[col];
#pragma unroll
      for (int rr = 0; rr < 4; ++rr) {
        const int row = m0 + wm + ri * 16 + hi * 4 + rr;
        __builtin_nontemporal_store(acc[ri][ci][rr] + bv, &Op[row * Ntot + col]);
      }
    }
}

// ---------------------------------------------------------------- fused prep
// r19 version verbatim:
//   [0, 6144)        conv8 x -> xb (nt loads)
//   [6144, 6198)     conv8 qkv_w -> qkv_wb
//   [6198, 6216)     conv8 proj_w -> proj_wb
//   [6216, 7240)     maskT (LDS-tiled 64x64 transpose, x log2e, bf16)
//   [7240, 8682)     cpb1 (one wave per (r,h), shfl_xor reduce)
__global__ __launch_bounds__(256) void k_prep(
    const float* __restrict__ x, bf16* __restrict__ xb,
    const float* __restrict__ qkv_w, bf16* __restrict__ qkv_wb,
    const float* __restrict__ proj_w, bf16* __restrict__ proj_wb,
    const float* __restrict__ mask, bf16* __restrict__ maskT,
    const float* __restrict__ ct, const float* __restrict__ w1,
    const float* __restrict__ b1, const float* __restrict__ w2,
    float* __restrict__ bt) {
  __shared__ float tile[64][65];
  const int bid = blockIdx.x;
  if (bid < 6216) {
    const float* in;
    bf16* o;
    int vb;
    bool nt = false;
    if (bid < 6144) { in = x; o = xb; vb = bid; nt = true; }
    else if (bid < 6198) { in = qkv_w; o = qkv_wb; vb = bid - 6144; }
    else { in = proj_w; o = proj_wb; vb = bid - 6198; }
    const int i = (vb * 256 + threadIdx.x) * 8;
    f32x4 a, b;
    if (nt) {
      a = __builtin_nontemporal_load(reinterpret_cast<const f32x4*>(&in[i]));
      b = __builtin_nontemporal_load(reinterpret_cast<const f32x4*>(&in[i + 4]));
    } else {
      a = *reinterpret_cast<const f32x4*>(&in[i]);
      b = *reinterpret_cast<const f32x4*>(&in[i + 4]);
    }
    bf16x8 v;
    v[0] = (bf16)a[0]; v[1] = (bf16)a[1]; v[2] = (bf16)a[2]; v[3] = (bf16)a[3];
    v[4] = (bf16)b[0]; v[5] = (bf16)b[1]; v[6] = (bf16)b[2]; v[7] = (bf16)b[3];
    *reinterpret_cast<bf16x8*>(&o[i]) = v;
  } else if (bid < 7240) {
    const int rem = bid - 6216;
    const int mb = rem >> 4;
    const int it = (rem & 15) >> 2, jt = rem & 3;
    const int tx = threadIdx.x & 63, ty = threadIdx.x >> 6;
    const float* mp = mask + mb * 65536;
#pragma unroll
    for (int rr = 0; rr < 16; ++rr)
      tile[rr * 4 + ty][tx] = mp[(it * 64 + rr * 4 + ty) * 256 + jt * 64 + tx];
    __syncthreads();
    bf16* op = maskT + mb * 65536;
#pragma unroll
    for (int rr = 0; rr < 16; ++rr)
      op[(jt * 64 + rr * 4 + ty) * 256 + it * 64 + tx] = (bf16)(LOG2E * tile[tx][rr * 4 + ty]);
  } else {
    // cpb1: bt[r][h] = (relu(ct[r] @ w1^T + b1) @ w2^T)[h], one wave per out
    const int wid = (bid - 7240) * 4 + (threadIdx.x >> 6);
    if (wid < 5766) {
      const int r = wid / 6, hh = wid % 6;
      const int lane = threadIdx.x & 63;
      const float t0 = ct[r * 2], t1 = ct[r * 2 + 1];
      float acc = 0.f;
#pragma unroll
      for (int jj = 0; jj < 8; ++jj) {
        const int j = lane + jj * 64;
        float hv = fmaf(w1[j * 2], t0, fmaf(w1[j * 2 + 1], t1, b1[j]));
        hv = fmaxf(hv, 0.f);
        acc = fmaf(hv, w2[hh * 512 + j], acc);
      }
      acc += __shfl_xor(acc, 1);
      acc += __shfl_xor(acc, 2);
      acc += __shfl_xor(acc, 4);
      acc += __shfl_xor(acc, 8);
      acc += __shfl_xor(acc, 16);
      acc += __shfl_xor(acc, 32);
      if (lane == 0) bt[wid] = acc;
    }
  }
}

// ---------------------------------------------------------------- attention
// r20: (A) HALF-SPLIT blocks — 3072 blocks, each does 2 of the 4 row-groups
// (hf = bid>=1536). Fixes the per-CU round quantization: 6 blocks in 4 slots
// was 2 rounds @75% slot utilization; 12 half-blocks = 3 full rounds @100%.
// Cost: K/V staged twice per (b,h) (~+49MB L3-resident; attn is at 9.7% HBM
// so affordable). (B) K staging via global_load_lds (r11-GEMM proven
// pattern): linear LDS dest (elem idx = p*2048 + t*8), XOR pre-applied to
// the global source column. V staging unchanged (r13 ledger). Per-wave
// compute code byte-identical to r17's frozen version.
__global__ __launch_bounds__(256) void k_attn(const bf16* __restrict__ qkv,
                                              const bf16* __restrict__ maskT,
                                              const float* __restrict__ biasfT,
                                              bf16* __restrict__ aout) {
  __shared__ bf16 ksh[256 * 32];   // 16 KB
  __shared__ bf16 vts[32 * 256];   // 16 KB
  __shared__ bf16 ps[4 * 16 * 64]; //  8 KB

  // ---- half index + XCD-aware remap (bijective): bid -> (b, h)
  const int bid0 = blockIdx.x;
  const int hf = (bid0 >= 1536) ? 1 : 0;   // which q-half of the (b,h) pair
  const int bid = bid0 - hf * 1536;        // [0,1536), same XCD map as r17
  const int x = bid & 7, i = bid >> 3;     // i in [0,192)
  const int mb = x * 8 + i / 24;           // 8 masks per XCD
  const int rem = i % 24;
  const int b = (rem / 6) * 64 + mb;       // b & 63 == mb
  const int h = rem % 6;
  const int t = threadIdx.x;

  // ---- staging: K via global_load_lds (pre-swizzled source col, linear
  // dest = p*2048 + t*8 elements); V reg-staged scalar transpose (as r17)
  const int rsub = t >> 2;
  const int c4s = t & 3;
#pragma unroll
  for (int p = 0; p < 4; ++p) {
    const int row = p * 64 + rsub;
    const int csw = (c4s * 8) ^ ((((row >> 1) & 3)) << 3);
    GLOAD_LDS(&qkv[(b * 256 + row) * 576 + h * 32 + 192 + csw], &ksh[p * 2048 + t * 8]);
    bf16x8 v = *reinterpret_cast<const bf16x8*>(
        &qkv[(b * 256 + row) * 576 + h * 32 + 384 + c4s * 8]);
#pragma unroll
    for (int jj = 0; jj < 8; ++jj) vts[vt_idx(c4s * 8 + jj, row)] = v[jj];
  }
  __syncthreads();

  const int w = t >> 6, lane = t & 63, lo = lane & 15, hi = lane >> 4;
  const float* bT = biasfT + (h << 16);
  const bf16* mT = maskT + (mb << 16);
  const bf16* qbase = qkv + (b * 256) * 576 + h * 32;

  // prefetch q fragment for the wave's first row group (rg0 = hf*8 + w)
  bf16x8 afn = *reinterpret_cast<const bf16x8*>(
      &qbase[((hf * 8 + w) * 16 + lo) * 576 + hi * 8]);

  // addend prefetch for first row group, ph=0
  f32x4 bvp[4];
  bf16x4 mvp[4];
  {
    const int rbase0 = (hf * 8 + w) * 16 + hi * 4;
#pragma unroll
    for (int c = 0; c < 4; ++c) {
      const int col = c * 16 + lo;
      bvp[c] = *reinterpret_cast<const f32x4*>(&bT[col * 256 + rbase0]);
      mvp[c] = *reinterpret_cast<const bf16x4*>(&mT[col * 256 + rbase0]);
    }
  }

  for (int rgi = 0; rgi < 2; ++rgi) {
    const int rg = (hf * 2 + rgi) * 4 + w;  // this wave's 16-row group
    const int rbase = rg * 16 + hi * 4;
    const bf16x8 af = afn;
    if (rgi < 1)  // issue next q load early (off the critical path)
      afn = *reinterpret_cast<const bf16x8*>(&qbase[((rg + 4) * 16 + lo) * 576 + hi * 8]);

    f32x4 po0 = {0.f, 0.f, 0.f, 0.f}, po1 = {0.f, 0.f, 0.f, 0.f};
    float sum[4] = {0.f, 0.f, 0.f, 0.f};

#pragma unroll
    for (int ph = 0; ph < 4; ++ph) {
      // ---- consume this phase's prefetched addends
      f32x4 bv[4];
      bf16x4 mv[4];
#pragma unroll
      for (int c = 0; c < 4; ++c) { bv[c] = bvp[c]; mv[c] = mvp[c]; }
      // ---- issue NEXT phase's addend loads (hidden under MFMA+exp below)
      if (ph < 3) {
#pragma unroll
        for (int c = 0; c < 4; ++c) {
          const int col = (ph + 1) * 64 + c * 16 + lo;
          bvp[c] = *reinterpret_cast<const f32x4*>(&bT[col * 256 + rbase]);
          mvp[c] = *reinterpret_cast<const bf16x4*>(&mT[col * 256 + rbase]);
        }
      } else if (rgi < 1) {  // first phase of the next row group (rbase+64)
#pragma unroll
        for (int c = 0; c < 4; ++c) {
          const int col = c * 16 + lo;
          bvp[c] = *reinterpret_cast<const f32x4*>(&bT[col * 256 + rbase + 64]);
          mvp[c] = *reinterpret_cast<const bf16x4*>(&mT[col * 256 + rbase + 64]);
        }
      }
      // ---- k fragments + S MFMAs
      bf16x8 kf[4];
#pragma unroll
      for (int c4i = 0; c4i < 4; ++c4i) {
        const int ct = ph * 4 + c4i;
        kf[c4i] = *reinterpret_cast<const bf16x8*>(&ksh[qk_idx(ct * 16 + lo, hi * 8)]);
      }
      f32x4 a[4];
#pragma unroll
      for (int c4i = 0; c4i < 4; ++c4i) {
        f32x4 z = {0.f, 0.f, 0.f, 0.f};
        a[c4i] = __builtin_amdgcn_mfma_f32_16x16x32_bf16(af, kf[c4i], z, 0, 0, 0);
      }
      // ---- fused addend+exp2+sum+p-store (unnormalized; raw v_exp_f32)
#pragma unroll
      for (int c4i = 0; c4i < 4; ++c4i)
#pragma unroll
        for (int rr = 0; rr < 4; ++rr) {
          const float s = a[c4i][rr] + bv[c4i][rr] + (float)mv[c4i][rr];
          const float p = __builtin_amdgcn_exp2f(s);
          sum[rr] += p;
          ps[p_idx4(w, hi * 4 + rr, c4i * 16 + lo)] = (bf16)p;
        }
      // ---- PV quarter (same-wave LDS producer/consumer; no barrier)
#pragma unroll
      for (int kb = 0; kb < 2; ++kb) {
        const bf16x8 pa = *reinterpret_cast<const bf16x8*>(&ps[p_idx4(w, lo, kb * 32 + hi * 8)]);
        const bf16x8 b0 = *reinterpret_cast<const bf16x8*>(&vts[vt_idx(lo, ph * 64 + kb * 32 + hi * 8)]);
        const bf16x8 b1 = *reinterpret_cast<const bf16x8*>(&vts[vt_idx(16 + lo, ph * 64 + kb * 32 + hi * 8)]);
        po0 = __builtin_amdgcn_mfma_f32_16x16x32_bf16(pa, b0, po0, 0, 0, 0);
        po1 = __builtin_amdgcn_mfma_f32_16x16x32_bf16(pa, b1, po1, 0, 0, 0);
      }
    }
    // ---- row-sum reduce across the 16 col-lanes, then normalize po
#pragma unroll
    for (int rr = 0; rr < 4; ++rr) {
      float s = sum[rr];
      s += __shfl_xor(s, 1, 16);
      s += __shfl_xor(s, 2, 16);
      s += __shfl_xor(s, 4, 16);
      s += __shfl_xor(s, 8, 16);
      sum[rr] = 1.f / s;
    }
    // ---- write attn-out (b, n, h*32+d) bf16
#pragma unroll
    for (int rr = 0; rr < 4; ++rr) {
      const int ob = (b * 256 + rbase + rr) * 192 + h * 32;
      aout[ob + lo] = (bf16)(po0[rr] * sum[rr]);
      aout[ob + 16 + lo] = (bf16)(po1[rr] * sum[rr]);
    }
  }
}

// ---------------------------------------------------------------- launcher
extern "C" void kernel_launch(void* const* d_in, const int* in_sizes, int n_in,
                              void* d_out, int out_size, void* d_ws, size_t ws_size,
                              hipStream_t stream) {
  const float* x      = (const float*)d_in[0];
  const float* mask   = (const float*)d_in[1];
  const float* qkv_w  = (const float*)d_in[2];
  const float* qkv_b  = (const float*)d_in[3];
  const float* proj_w = (const float*)d_in[4];
  const float* proj_b = (const float*)d_in[5];
  const float* lsc    = (const float*)d_in[6];
  const float* cpb_w1 = (const float*)d_in[7];
  const float* cpb_b1 = (const float*)d_in[8];
  const float* cpb_w2 = (const float*)d_in[9];
  const float* ctab   = (const float*)d_in[10];
  const int*   relidx = (const int*)d_in[11];

  char* ws = (char*)d_ws;
  bf16*  qkvb   = (bf16*)(ws);                      // 65536*576*2 = 75,497,472
  // xb and aoutb SHARE this slot (disjoint lifetimes, stream-ordered):
  bf16*  xb     = (bf16*)(ws + 75497472);           // 12582912*2  = 25,165,824
  bf16*  aoutb  = (bf16*)(ws + 75497472);           // 65536*192*2 = 25,165,824
  float* biasfT = (float*)(ws + 100663296);         // 6*65536*4   =  1,572,864  (transposed, x log2e)
  bf16*  maskTb = (bf16*)(ws + 102236160);          // 64*65536*2  =  8,388,608  (transposed, x log2e)
  float* bt     = (float*)(ws + 110624768);         // 961*6*4     =     23,064
  bf16*  qkv_wb = (bf16*)(ws + 110647840);          // 576*192*2   =    221,184
  bf16*  proj_wb= (bf16*)(ws + 110869024);          // 192*192*2   =     73,728

  k_prep<<<8682, 256, 0, stream>>>(x, xb, qkv_w, qkv_wb, proj_w, proj_wb,
                                   mask, maskTb, ctab, cpb_w1, cpb_b1, cpb_w2, bt);
  k_qkv<<<10752, 256, 0, stream>>>(xb, qkv_wb, qkv_b, lsc, qkvb, bt, relidx, biasfT);
  k_attn<<<3072, 256, 0, stream>>>(qkvb, maskTb, biasfT, aoutb);
  k_gemm<3><<<3072, 256, 0, stream>>>(aoutb, proj_wb, proj_b, (float*)d_out, 192);
}

// Round 21
// 186.894 us; speedup vs baseline: 1.0162x; 1.0162x over previous
//
#include <hip/hip_runtime.h>

using bf16 = __bf16;
typedef bf16 bf16x4 __attribute__((ext_vector_type(4)));
typedef bf16 bf16x8 __attribute__((ext_vector_type(8)));
typedef float f32x4 __attribute__((ext_vector_type(4)));

// ---------------------------------------------------------------- helpers
// GEMM LDS tiles: row stride 192 bf16 (384B, bank-aligned). XOR row&7 into
// element bits [3:5] -> 8 distinct 16B slots per 8 rows.
__device__ __forceinline__ int swz192(int row, int col) {
  return row * 192 + (col ^ ((row & 7) << 3));
}
// attention k tile: 256 rows x 32 bf16 (64B rows). Pack 2 rows per 128B block,
// XOR (row>>1)&3 into col bits [3:4].
__device__ __forceinline__ int qk_idx(int row, int col) {
  return (row >> 1) * 64 + (row & 1) * 32 + (col ^ (((row >> 1) & 3) << 3));
}
// V^T tile: 32 rows(d) x 256 bf16. Rotate n by 16*(d>>3); XOR (d&7)<<3
// (bank conflicts 3.5M -> 0.96M measured in r4). SCALAR writes only —
// r13's packed-b32 variant FAILED correctness; do not retry (ledger).
__device__ __forceinline__ int vt_idx(int d, int n) {
  return d * 256 + (((n + ((d >> 3) << 4)) & 255) ^ ((d & 7) << 3));
}
// P tile (per wave): 16 rows x 64 bf16 (K=64 quarter) -> XOR r&7 into 16B slots.
__device__ __forceinline__ int p_idx4(int wv, int r, int c) {
  return wv * 1024 + r * 64 + (c ^ ((r & 7) << 3));
}

#define LOG2E 1.44269504088896f
#define GLOAD_LDS(src, dst)                                                     \
  __builtin_amdgcn_global_load_lds(                                             \
      (const __attribute__((address_space(1))) void*)(src),                     \
      (__attribute__((address_space(3))) void*)(dst), 16, 0, 0)

// ---------------------------------------------------------------- QKV GEMM + cpbT
// r21: cpbT blocks dispatched FIRST (bids [0,1536)) so the short memory-bound
// gather overlaps the GEMM wavefront fill instead of running as a serial tail
// after the GEMM blocks drain. GEMM bids shifted by 1536 (divisible by 8 ->
// XCD swizzle pattern preserved). GEMM body is r11 verbatim: BM=BN=64,
// gload_lds staging with pre-swizzled source (rule #21), XCD-co-locating
// swizzle, q/k normalize + logit-scale/log2e folding in the epilogue.
__global__ __launch_bounds__(256) void k_qkv(const bf16* __restrict__ A,
                                             const bf16* __restrict__ W,
                                             const float* __restrict__ bias,
                                             const float* __restrict__ lsc,
                                             bf16* __restrict__ Op,
                                             const float* __restrict__ bt,
                                             const int* __restrict__ rel,
                                             float* __restrict__ biasfT) {
  __shared__ bf16 As[64 * 192];
  __shared__ bf16 Bs[64 * 192];
  const int bid = blockIdx.x;
  const int t = threadIdx.x;

  if (bid < 1536) {  // ---- cpbT: biasfT[h][j][i] = l2e*16*sig(bt[rel[i][j]][h])
    const int idx = bid * 256 + t;  // 6*65536 exactly
    const int hh = idx >> 16;
    const int jj = (idx >> 8) & 255;
    const int i = idx & 255;
    const float v = bt[rel[i * 256 + jj] * 6 + hh];
    biasfT[idx] = LOG2E * 16.f / (1.f + __builtin_amdgcn_exp2f(-LOG2E * v));
    return;
  }

  const int gbid = bid - 1536;      // [0, 9216)
  const int xcd = gbid & 7;
  const int j = gbid >> 3;
  const int m0 = (xcd + 8 * (j / 9)) * 64;
  const int n0 = (j % 9) * 64;

#pragma unroll
  for (int i = 0; i < 6; ++i) {
    const int f = t + i * 256;
    const int row = f / 24, c8 = f % 24;
    const int csw = (c8 ^ (row & 7)) * 8;  // pre-swizzled source chunk
    GLOAD_LDS(&A[(m0 + row) * 192 + csw], &As[f * 8]);
    GLOAD_LDS(&W[(n0 + row) * 192 + csw], &Bs[f * 8]);
  }
  __syncthreads();

  const int w = t >> 6, lane = t & 63, lo = lane & 15, hi = lane >> 4;
  const int wm = (w >> 1) * 32, wn = (w & 1) * 32;
  f32x4 acc[2][2];
#pragma unroll
  for (int a = 0; a < 2; ++a)
#pragma unroll
    for (int c = 0; c < 2; ++c) acc[a][c] = f32x4{0.f, 0.f, 0.f, 0.f};

#pragma unroll
  for (int ks = 0; ks < 6; ++ks) {
    const int k0 = ks * 32 + hi * 8;
    bf16x8 af[2], bfr[2];
#pragma unroll
    for (int ri = 0; ri < 2; ++ri)
      af[ri] = *reinterpret_cast<const bf16x8*>(&As[swz192(wm + ri * 16 + lo, k0)]);
#pragma unroll
    for (int ci = 0; ci < 2; ++ci)
      bfr[ci] = *reinterpret_cast<const bf16x8*>(&Bs[swz192(wn + ci * 16 + lo, k0)]);
#pragma unroll
    for (int ri = 0; ri < 2; ++ri)
#pragma unroll
      for (int ci = 0; ci < 2; ++ci)
        acc[ri][ci] = __builtin_amdgcn_mfma_f32_16x16x32_bf16(af[ri], bfr[ci], acc[ri][ci], 0, 0, 0);
  }

  const int cb = n0 + wn;           // wave's 32-col block start (one head group)
  const bool donorm = (cb < 384);   // q or k
  float smul = 1.f;
  if (cb < 192)                     // q: fold logit scale AND log2e (exp->exp2)
    smul = expf(fminf(lsc[cb >> 5], 4.605170185988091f)) * LOG2E;
  const int col0 = cb + lo;
  const float b0 = bias[col0], b1 = bias[col0 + 16];
#pragma unroll
  for (int ri = 0; ri < 2; ++ri)
#pragma unroll
    for (int rr = 0; rr < 4; ++rr) {
      float v0 = acc[ri][0][rr] + b0;
      float v1 = acc[ri][1][rr] + b1;
      if (donorm) {
        float ss = v0 * v0 + v1 * v1;
        ss += __shfl_xor(ss, 1, 16);
        ss += __shfl_xor(ss, 2, 16);
        ss += __shfl_xor(ss, 4, 16);
        ss += __shfl_xor(ss, 8, 16);
        const float rn = smul / fmaxf(sqrtf(ss), 1e-12f);
        v0 *= rn;
        v1 *= rn;
      }
      const int row = m0 + wm + ri * 16 + hi * 4 + rr;
      Op[row * 576 + col0] = (bf16)v0;
      Op[row * 576 + col0 + 16] = (bf16)v1;
    }
}

// ---------------------------------------------------------------- proj GEMM
// r11 version verbatim. out f32 nt-stored (never re-read).
template <int NT>
__global__ __launch_bounds__(256) void k_gemm(const bf16* __restrict__ A,
                                              const bf16* __restrict__ W,
                                              const float* __restrict__ bias,
                                              float* __restrict__ Op, int Ntot) {
  __shared__ bf16 As[64 * 192];
  __shared__ bf16 Bs[64 * 192];
  const int bid = blockIdx.x;
  const int xcd = bid & 7;
  const int j = bid >> 3;
  const int m0 = (xcd + 8 * (j / NT)) * 64;
  const int n0 = (j % NT) * 64;
  const int t = threadIdx.x;

#pragma unroll
  for (int i = 0; i < 6; ++i) {
    const int f = t + i * 256;
    const int row = f / 24, c8 = f % 24;
    const int csw = (c8 ^ (row & 7)) * 8;  // pre-swizzled source chunk
    GLOAD_LDS(&A[(m0 + row) * 192 + csw], &As[f * 8]);
    GLOAD_LDS(&W[(n0 + row) * 192 + csw], &Bs[f * 8]);
  }
  __syncthreads();

  const int w = t >> 6, lane = t & 63, lo = lane & 15, hi = lane >> 4;
  const int wm = (w >> 1) * 32, wn = (w & 1) * 32;
  f32x4 acc[2][2];
#pragma unroll
  for (int a = 0; a < 2; ++a)
#pragma unroll
    for (int c = 0; c < 2; ++c) acc[a][c] = f32x4{0.f, 0.f, 0.f, 0.f};

#pragma unroll
  for (int ks = 0; ks < 6; ++ks) {
    const int k0 = ks * 32 + hi * 8;
    bf16x8 af[2], bfr[2];
#pragma unroll
    for (int ri = 0; ri < 2; ++ri)
      af[ri] = *reinterpret_cast<const bf16x8*>(&As[swz192(wm + ri * 16 + lo, k0)]);
#pragma unroll
    for (int ci = 0; ci < 2; ++ci)
      bfr[ci] = *reinterpret_cast<const bf16x8*>(&Bs[swz192(wn + ci * 16 + lo, k0)]);
#pragma unroll
    for (int ri = 0; ri < 2; ++ri)
#pragma unroll
      for (int ci = 0; ci < 2; ++ci)
        acc[ri][ci] = __builtin_amdgcn_mfma_f32_16x16x32_bf16(af[ri], bfr[ci], acc[ri][ci], 0, 0, 0);
  }

#pragma unroll
  for (int ri = 0; ri < 2; ++ri)
#pragma unroll
    for (int ci = 0; ci < 2; ++ci) {
      const int col = n0 + wn + ci * 16 + lo;
      const float bv = bias[col];
#pragma unroll
      for (int rr = 0; rr < 4; ++rr) {
        const int row = m0 + wm + ri * 16 + hi * 4 + rr;
        __builtin_nontemporal_store(acc[ri][ci][rr] + bv, &Op[row * Ntot + col]);
      }
    }
}

// ---------------------------------------------------------------- fused prep
// r19 version verbatim:
//   [0, 6144)        conv8 x -> xb (nt loads)
//   [6144, 6198)     conv8 qkv_w -> qkv_wb
//   [6198, 6216)     conv8 proj_w -> proj_wb
//   [6216, 7240)     maskT (LDS-tiled 64x64 transpose, x log2e, bf16)
//   [7240, 8682)     cpb1 (one wave per (r,h), shfl_xor reduce)
__global__ __launch_bounds__(256) void k_prep(
    const float* __restrict__ x, bf16* __restrict__ xb,
    const float* __restrict__ qkv_w, bf16* __restrict__ qkv_wb,
    const float* __restrict__ proj_w, bf16* __restrict__ proj_wb,
    const float* __restrict__ mask, bf16* __restrict__ maskT,
    const float* __restrict__ ct, const float* __restrict__ w1,
    const float* __restrict__ b1, const float* __restrict__ w2,
    float* __restrict__ bt) {
  __shared__ float tile[64][65];
  const int bid = blockIdx.x;
  if (bid < 6216) {
    const float* in;
    bf16* o;
    int vb;
    bool nt = false;
    if (bid < 6144) { in = x; o = xb; vb = bid; nt = true; }
    else if (bid < 6198) { in = qkv_w; o = qkv_wb; vb = bid - 6144; }
    else { in = proj_w; o = proj_wb; vb = bid - 6198; }
    const int i = (vb * 256 + threadIdx.x) * 8;
    f32x4 a, b;
    if (nt) {
      a = __builtin_nontemporal_load(reinterpret_cast<const f32x4*>(&in[i]));
      b = __builtin_nontemporal_load(reinterpret_cast<const f32x4*>(&in[i + 4]));
    } else {
      a = *reinterpret_cast<const f32x4*>(&in[i]);
      b = *reinterpret_cast<const f32x4*>(&in[i + 4]);
    }
    bf16x8 v;
    v[0] = (bf16)a[0]; v[1] = (bf16)a[1]; v[2] = (bf16)a[2]; v[3] = (bf16)a[3];
    v[4] = (bf16)b[0]; v[5] = (bf16)b[1]; v[6] = (bf16)b[2]; v[7] = (bf16)b[3];
    *reinterpret_cast<bf16x8*>(&o[i]) = v;
  } else if (bid < 7240) {
    const int rem = bid - 6216;
    const int mb = rem >> 4;
    const int it = (rem & 15) >> 2, jt = rem & 3;
    const int tx = threadIdx.x & 63, ty = threadIdx.x >> 6;
    const float* mp = mask + mb * 65536;
#pragma unroll
    for (int rr = 0; rr < 16; ++rr)
      tile[rr * 4 + ty][tx] = mp[(it * 64 + rr * 4 + ty) * 256 + jt * 64 + tx];
    __syncthreads();
    bf16* op = maskT + mb * 65536;
#pragma unroll
    for (int rr = 0; rr < 16; ++rr)
      op[(jt * 64 + rr * 4 + ty) * 256 + it * 64 + tx] = (bf16)(LOG2E * tile[tx][rr * 4 + ty]);
  } else {
    // cpb1: bt[r][h] = (relu(ct[r] @ w1^T + b1) @ w2^T)[h], one wave per out
    const int wid = (bid - 7240) * 4 + (threadIdx.x >> 6);
    if (wid < 5766) {
      const int r = wid / 6, hh = wid % 6;
      const int lane = threadIdx.x & 63;
      const float t0 = ct[r * 2], t1 = ct[r * 2 + 1];
      float acc = 0.f;
#pragma unroll
      for (int jj = 0; jj < 8; ++jj) {
        const int j = lane + jj * 64;
        float hv = fmaf(w1[j * 2], t0, fmaf(w1[j * 2 + 1], t1, b1[j]));
        hv = fmaxf(hv, 0.f);
        acc = fmaf(hv, w2[hh * 512 + j], acc);
      }
      acc += __shfl_xor(acc, 1);
      acc += __shfl_xor(acc, 2);
      acc += __shfl_xor(acc, 4);
      acc += __shfl_xor(acc, 8);
      acc += __shfl_xor(acc, 16);
      acc += __shfl_xor(acc, 32);
      if (lane == 0) bt[wid] = acc;
    }
  }
}

// ---------------------------------------------------------------- attention
// r17 version verbatim (best attn: 105.8us, VGPR 128, cross-phase addend
// prefetch, f32 bias, raw v_exp_f32 exp2). FROZEN — 11 variants tried;
// distributed-latency-bound (MfmaUtil 5%, VALU 30%, HBM 10%, occupancy
// capped at the VGPR/LDS corner). r20's half-split duplicated staging and
// regressed; do not retry splits that restage K/V (ledger).
__global__ __launch_bounds__(256) void k_attn(const bf16* __restrict__ qkv,
                                              const bf16* __restrict__ maskT,
                                              const float* __restrict__ biasfT,
                                              bf16* __restrict__ aout) {
  __shared__ bf16 ksh[256 * 32];   // 16 KB
  __shared__ bf16 vts[32 * 256];   // 16 KB
  __shared__ bf16 ps[4 * 16 * 64]; //  8 KB

  // ---- XCD-aware remap (bijective): bid -> (b, h)
  const int bid = blockIdx.x;
  const int x = bid & 7, i = bid >> 3;       // i in [0,192)
  const int mb = x * 8 + i / 24;             // 8 masks per XCD
  const int rem = i % 24;
  const int b = (rem / 6) * 64 + mb;         // b & 63 == mb
  const int h = rem % 6;
  const int t = threadIdx.x;

  // ---- staging (k, v): rows t>>2 (+p*64), 16B chunk t&3
  const int rsub = t >> 2;
  const int c4s = t & 3;
#pragma unroll
  for (int p = 0; p < 4; ++p) {
    const int row = p * 64 + rsub;
    const int base = (b * 256 + row) * 576 + h * 32 + c4s * 8;
    *reinterpret_cast<bf16x8*>(&ksh[qk_idx(row, c4s * 8)]) =
        *reinterpret_cast<const bf16x8*>(&qkv[base + 192]);
    bf16x8 v = *reinterpret_cast<const bf16x8*>(&qkv[base + 384]);
#pragma unroll
    for (int jj = 0; jj < 8; ++jj) vts[vt_idx(c4s * 8 + jj, row)] = v[jj];
  }
  __syncthreads();

  const int w = t >> 6, lane = t & 63, lo = lane & 15, hi = lane >> 4;
  const float* bT = biasfT + (h << 16);
  const bf16* mT = maskT + (mb << 16);
  const bf16* qbase = qkv + (b * 256) * 576 + h * 32;

  // prefetch q fragment for the wave's first row group
  bf16x8 afn = *reinterpret_cast<const bf16x8*>(&qbase[(w * 16 + lo) * 576 + hi * 8]);

  // addend prefetch for rgi=0, ph=0
  f32x4 bvp[4];
  bf16x4 mvp[4];
  {
    const int rbase0 = w * 16 + hi * 4;
#pragma unroll
    for (int c = 0; c < 4; ++c) {
      const int col = c * 16 + lo;
      bvp[c] = *reinterpret_cast<const f32x4*>(&bT[col * 256 + rbase0]);
      mvp[c] = *reinterpret_cast<const bf16x4*>(&mT[col * 256 + rbase0]);
    }
  }

  for (int rgi = 0; rgi < 4; ++rgi) {
    const int rg = rgi * 4 + w;  // this wave's 16-row group; private -> no barriers
    const int rbase = rg * 16 + hi * 4;
    const bf16x8 af = afn;
    if (rgi < 3)  // issue next q load early (off the critical path)
      afn = *reinterpret_cast<const bf16x8*>(&qbase[((rg + 4) * 16 + lo) * 576 + hi * 8]);

    f32x4 po0 = {0.f, 0.f, 0.f, 0.f}, po1 = {0.f, 0.f, 0.f, 0.f};
    float sum[4] = {0.f, 0.f, 0.f, 0.f};

#pragma unroll
    for (int ph = 0; ph < 4; ++ph) {
      // ---- consume this phase's prefetched addends
      f32x4 bv[4];
      bf16x4 mv[4];
#pragma unroll
      for (int c = 0; c < 4; ++c) { bv[c] = bvp[c]; mv[c] = mvp[c]; }
      // ---- issue NEXT phase's addend loads (hidden under MFMA+exp below)
      if (ph < 3) {
#pragma unroll
        for (int c = 0; c < 4; ++c) {
          const int col = (ph + 1) * 64 + c * 16 + lo;
          bvp[c] = *reinterpret_cast<const f32x4*>(&bT[col * 256 + rbase]);
          mvp[c] = *reinterpret_cast<const bf16x4*>(&mT[col * 256 + rbase]);
        }
      } else if (rgi < 3) {  // first phase of the next row group (rbase+64)
#pragma unroll
        for (int c = 0; c < 4; ++c) {
          const int col = c * 16 + lo;
          bvp[c] = *reinterpret_cast<const f32x4*>(&bT[col * 256 + rbase + 64]);
          mvp[c] = *reinterpret_cast<const bf16x4*>(&mT[col * 256 + rbase + 64]);
        }
      }
      // ---- k fragments + S MFMAs
      bf16x8 kf[4];
#pragma unroll
      for (int c4i = 0; c4i < 4; ++c4i) {
        const int ct = ph * 4 + c4i;
        kf[c4i] = *reinterpret_cast<const bf16x8*>(&ksh[qk_idx(ct * 16 + lo, hi * 8)]);
      }
      f32x4 a[4];
#pragma unroll
      for (int c4i = 0; c4i < 4; ++c4i) {
        f32x4 z = {0.f, 0.f, 0.f, 0.f};
        a[c4i] = __builtin_amdgcn_mfma_f32_16x16x32_bf16(af, kf[c4i], z, 0, 0, 0);
      }
      // ---- fused addend+exp2+sum+p-store (unnormalized; raw v_exp_f32)
#pragma unroll
      for (int c4i = 0; c4i < 4; ++c4i)
#pragma unroll
        for (int rr = 0; rr < 4; ++rr) {
          const float s = a[c4i][rr] + bv[c4i][rr] + (float)mv[c4i][rr];
          const float p = __builtin_amdgcn_exp2f(s);
          sum[rr] += p;
          ps[p_idx4(w, hi * 4 + rr, c4i * 16 + lo)] = (bf16)p;
        }
      // ---- PV quarter (same-wave LDS producer/consumer; no barrier)
#pragma unroll
      for (int kb = 0; kb < 2; ++kb) {
        const bf16x8 pa = *reinterpret_cast<const bf16x8*>(&ps[p_idx4(w, lo, kb * 32 + hi * 8)]);
        const bf16x8 b0 = *reinterpret_cast<const bf16x8*>(&vts[vt_idx(lo, ph * 64 + kb * 32 + hi * 8)]);
        const bf16x8 b1 = *reinterpret_cast<const bf16x8*>(&vts[vt_idx(16 + lo, ph * 64 + kb * 32 + hi * 8)]);
        po0 = __builtin_amdgcn_mfma_f32_16x16x32_bf16(pa, b0, po0, 0, 0, 0);
        po1 = __builtin_amdgcn_mfma_f32_16x16x32_bf16(pa, b1, po1, 0, 0, 0);
      }
    }
    // ---- row-sum reduce across the 16 col-lanes, then normalize po
#pragma unroll
    for (int rr = 0; rr < 4; ++rr) {
      float s = sum[rr];
      s += __shfl_xor(s, 1, 16);
      s += __shfl_xor(s, 2, 16);
      s += __shfl_xor(s, 4, 16);
      s += __shfl_xor(s, 8, 16);
      sum[rr] = 1.f / s;
    }
    // ---- write attn-out (b, n, h*32+d) bf16
#pragma unroll
    for (int rr = 0; rr < 4; ++rr) {
      const int ob = (b * 256 + rbase + rr) * 192 + h * 32;
      aout[ob + lo] = (bf16)(po0[rr] * sum[rr]);
      aout[ob + 16 + lo] = (bf16)(po1[rr] * sum[rr]);
    }
  }
}

// ---------------------------------------------------------------- launcher
extern "C" void kernel_launch(void* const* d_in, const int* in_sizes, int n_in,
                              void* d_out, int out_size, void* d_ws, size_t ws_size,
                              hipStream_t stream) {
  const float* x      = (const float*)d_in[0];
  const float* mask   = (const float*)d_in[1];
  const float* qkv_w  = (const float*)d_in[2];
  const float* qkv_b  = (const float*)d_in[3];
  const float* proj_w = (const float*)d_in[4];
  const float* proj_b = (const float*)d_in[5];
  const float* lsc    = (const float*)d_in[6];
  const float* cpb_w1 = (const float*)d_in[7];
  const float* cpb_b1 = (const float*)d_in[8];
  const float* cpb_w2 = (const float*)d_in[9];
  const float* ctab   = (const float*)d_in[10];
  const int*   relidx = (const int*)d_in[11];

  char* ws = (char*)d_ws;
  bf16*  qkvb   = (bf16*)(ws);                      // 65536*576*2 = 75,497,472
  // xb and aoutb SHARE this slot (disjoint lifetimes, stream-ordered):
  bf16*  xb     = (bf16*)(ws + 75497472);           // 12582912*2  = 25,165,824
  bf16*  aoutb  = (bf16*)(ws + 75497472);           // 65536*192*2 = 25,165,824
  float* biasfT = (float*)(ws + 100663296);         // 6*65536*4   =  1,572,864  (transposed, x log2e)
  bf16*  maskTb = (bf16*)(ws + 102236160);          // 64*65536*2  =  8,388,608  (transposed, x log2e)
  float* bt     = (float*)(ws + 110624768);         // 961*6*4     =     23,064
  bf16*  qkv_wb = (bf16*)(ws + 110647840);          // 576*192*2   =    221,184
  bf16*  proj_wb= (bf16*)(ws + 110869024);          // 192*192*2   =     73,728

  k_prep<<<8682, 256, 0, stream>>>(x, xb, qkv_w, qkv_wb, proj_w, proj_wb,
                                   mask, maskTb, ctab, cpb_w1, cpb_b1, cpb_w2, bt);
  k_qkv<<<10752, 256, 0, stream>>>(xb, qkv_wb, qkv_b, lsc, qkvb, bt, relidx, biasfT);
  k_attn<<<1536, 256, 0, stream>>>(qkvb, maskTb, biasfT, aoutb);
  k_gemm<3><<<3072, 256, 0, stream>>>(aoutb, proj_wb, proj_b, (float*)d_out, 192);
}

// Round 22
// 182.633 us; speedup vs baseline: 1.0399x; 1.0233x over previous
//
#include <hip/hip_runtime.h>

using bf16 = __bf16;
typedef bf16 bf16x4 __attribute__((ext_vector_type(4)));
typedef bf16 bf16x8 __attribute__((ext_vector_type(8)));
typedef float f32x4 __attribute__((ext_vector_type(4)));

// ---------------------------------------------------------------- helpers
// GEMM LDS tiles: row stride 192 bf16 (384B, bank-aligned). XOR row&7 into
// element bits [3:5] -> 8 distinct 16B slots per 8 rows. 4-aligned runs stay
// contiguous (XOR touches bits >=3) -> bf16x4 stores legal (proven r2-r9).
__device__ __forceinline__ int swz192(int row, int col) {
  return row * 192 + (col ^ ((row & 7) << 3));
}
// attention k tile: 256 rows x 32 bf16 (64B rows). Pack 2 rows per 128B block,
// XOR (row>>1)&3 into col bits [3:4].
__device__ __forceinline__ int qk_idx(int row, int col) {
  return (row >> 1) * 64 + (row & 1) * 32 + (col ^ (((row >> 1) & 3) << 3));
}
// V^T tile: 32 rows(d) x 256 bf16. Rotate n by 16*(d>>3); XOR (d&7)<<3
// (bank conflicts 3.5M -> 0.96M measured in r4). SCALAR writes only —
// r13's packed-b32 variant FAILED correctness; do not retry (ledger).
__device__ __forceinline__ int vt_idx(int d, int n) {
  return d * 256 + (((n + ((d >> 3) << 4)) & 255) ^ ((d & 7) << 3));
}
// P tile (per wave): 16 rows x 64 bf16 (K=64 quarter) -> XOR r&7 into 16B slots.
__device__ __forceinline__ int p_idx4(int wv, int r, int c) {
  return wv * 1024 + r * 64 + (c ^ ((r & 7) << 3));
}

#define LOG2E 1.44269504088896f
#define GLOAD_LDS(src, dst)                                                     \
  __builtin_amdgcn_global_load_lds(                                             \
      (const __attribute__((address_space(1))) void*)(src),                     \
      (__attribute__((address_space(3))) void*)(dst), 16, 0, 0)

// ---------------------------------------------------------------- QKV GEMM + cpbT
// r22: A staged DIRECTLY from f32 x with in-register convert (r9's proven
// staging) — kills the x->xb pre-convert round-trip (100MB HBM + 6144 prep
// blocks). W keeps the gload_lds path (pre-converted bf16, pre-swizzled
// source, rule #21). cpbT range-merged at bids >=9216 (r19 ordering; r21's
// cpbT-first was null). XCD-co-locating swizzle; q/k normalize + logit-scale
// and log2e folding in the epilogue.
__global__ __launch_bounds__(256) void k_qkv(const float* __restrict__ A,
                                             const bf16* __restrict__ W,
                                             const float* __restrict__ bias,
                                             const float* __restrict__ lsc,
                                             bf16* __restrict__ Op,
                                             const float* __restrict__ bt,
                                             const int* __restrict__ rel,
                                             float* __restrict__ biasfT) {
  __shared__ bf16 As[64 * 192];
  __shared__ bf16 Bs[64 * 192];
  const int bid = blockIdx.x;
  const int t = threadIdx.x;

  if (bid >= 9216) {  // ---- cpbT: biasfT[h][j][i] = l2e*16*sig(bt[rel[i][j]][h])
    const int idx = (bid - 9216) * 256 + t;  // 6*65536 exactly
    const int hh = idx >> 16;
    const int jj = (idx >> 8) & 255;
    const int i = idx & 255;
    const float v = bt[rel[i * 256 + jj] * 6 + hh];
    biasfT[idx] = LOG2E * 16.f / (1.f + __builtin_amdgcn_exp2f(-LOG2E * v));
    return;
  }

  const int xcd = bid & 7;
  const int j = bid >> 3;
  const int m0 = (xcd + 8 * (j / 9)) * 64;
  const int n0 = (j % 9) * 64;

  // ---- W via global_load_lds (bf16, pre-swizzled source)
#pragma unroll
  for (int i = 0; i < 6; ++i) {
    const int f = t + i * 256;
    const int row = f / 24, c8 = f % 24;
    const int csw = (c8 ^ (row & 7)) * 8;
    GLOAD_LDS(&W[(n0 + row) * 192 + csw], &Bs[f * 8]);
  }
  // ---- A from f32 x, in-register convert (r9 pattern, proven r2-r9)
#pragma unroll
  for (int i = 0; i < 12; ++i) {
    const int f = t + i * 256;
    const int row = f / 48, c4 = f % 48;
    const f32x4 v = *reinterpret_cast<const f32x4*>(&A[(m0 + row) * 192 + c4 * 4]);
    bf16x4 hv;
    hv[0] = (bf16)v[0]; hv[1] = (bf16)v[1]; hv[2] = (bf16)v[2]; hv[3] = (bf16)v[3];
    *reinterpret_cast<bf16x4*>(&As[swz192(row, c4 * 4)]) = hv;
  }
  __syncthreads();

  const int w = t >> 6, lane = t & 63, lo = lane & 15, hi = lane >> 4;
  const int wm = (w >> 1) * 32, wn = (w & 1) * 32;
  f32x4 acc[2][2];
#pragma unroll
  for (int a = 0; a < 2; ++a)
#pragma unroll
    for (int c = 0; c < 2; ++c) acc[a][c] = f32x4{0.f, 0.f, 0.f, 0.f};

#pragma unroll
  for (int ks = 0; ks < 6; ++ks) {
    const int k0 = ks * 32 + hi * 8;
    bf16x8 af[2], bfr[2];
#pragma unroll
    for (int ri = 0; ri < 2; ++ri)
      af[ri] = *reinterpret_cast<const bf16x8*>(&As[swz192(wm + ri * 16 + lo, k0)]);
#pragma unroll
    for (int ci = 0; ci < 2; ++ci)
      bfr[ci] = *reinterpret_cast<const bf16x8*>(&Bs[swz192(wn + ci * 16 + lo, k0)]);
#pragma unroll
    for (int ri = 0; ri < 2; ++ri)
#pragma unroll
      for (int ci = 0; ci < 2; ++ci)
        acc[ri][ci] = __builtin_amdgcn_mfma_f32_16x16x32_bf16(af[ri], bfr[ci], acc[ri][ci], 0, 0, 0);
  }

  const int cb = n0 + wn;           // wave's 32-col block start (one head group)
  const bool donorm = (cb < 384);   // q or k
  float smul = 1.f;
  if (cb < 192)                     // q: fold logit scale AND log2e (exp->exp2)
    smul = expf(fminf(lsc[cb >> 5], 4.605170185988091f)) * LOG2E;
  const int col0 = cb + lo;
  const float b0 = bias[col0], b1 = bias[col0 + 16];
#pragma unroll
  for (int ri = 0; ri < 2; ++ri)
#pragma unroll
    for (int rr = 0; rr < 4; ++rr) {
      float v0 = acc[ri][0][rr] + b0;
      float v1 = acc[ri][1][rr] + b1;
      if (donorm) {
        float ss = v0 * v0 + v1 * v1;
        ss += __shfl_xor(ss, 1, 16);
        ss += __shfl_xor(ss, 2, 16);
        ss += __shfl_xor(ss, 4, 16);
        ss += __shfl_xor(ss, 8, 16);
        const float rn = smul / fmaxf(sqrtf(ss), 1e-12f);
        v0 *= rn;
        v1 *= rn;
      }
      const int row = m0 + wm + ri * 16 + hi * 4 + rr;
      Op[row * 576 + col0] = (bf16)v0;
      Op[row * 576 + col0 + 16] = (bf16)v1;
    }
}

// ---------------------------------------------------------------- proj GEMM
// r11 version verbatim. out f32 nt-stored (never re-read).
template <int NT>
__global__ __launch_bounds__(256) void k_gemm(const bf16* __restrict__ A,
                                              const bf16* __restrict__ W,
                                              const float* __restrict__ bias,
                                              float* __restrict__ Op, int Ntot) {
  __shared__ bf16 As[64 * 192];
  __shared__ bf16 Bs[64 * 192];
  const int bid = blockIdx.x;
  const int xcd = bid & 7;
  const int j = bid >> 3;
  const int m0 = (xcd + 8 * (j / NT)) * 64;
  const int n0 = (j % NT) * 64;
  const int t = threadIdx.x;

#pragma unroll
  for (int i = 0; i < 6; ++i) {
    const int f = t + i * 256;
    const int row = f / 24, c8 = f % 24;
    const int csw = (c8 ^ (row & 7)) * 8;  // pre-swizzled source chunk
    GLOAD_LDS(&A[(m0 + row) * 192 + csw], &As[f * 8]);
    GLOAD_LDS(&W[(n0 + row) * 192 + csw], &Bs[f * 8]);
  }
  __syncthreads();

  const int w = t >> 6, lane = t & 63, lo = lane & 15, hi = lane >> 4;
  const int wm = (w >> 1) * 32, wn = (w & 1) * 32;
  f32x4 acc[2][2];
#pragma unroll
  for (int a = 0; a < 2; ++a)
#pragma unroll
    for (int c = 0; c < 2; ++c) acc[a][c] = f32x4{0.f, 0.f, 0.f, 0.f};

#pragma unroll
  for (int ks = 0; ks < 6; ++ks) {
    const int k0 = ks * 32 + hi * 8;
    bf16x8 af[2], bfr[2];
#pragma unroll
    for (int ri = 0; ri < 2; ++ri)
      af[ri] = *reinterpret_cast<const bf16x8*>(&As[swz192(wm + ri * 16 + lo, k0)]);
#pragma unroll
    for (int ci = 0; ci < 2; ++ci)
      bfr[ci] = *reinterpret_cast<const bf16x8*>(&Bs[swz192(wn + ci * 16 + lo, k0)]);
#pragma unroll
    for (int ri = 0; ri < 2; ++ri)
#pragma unroll
      for (int ci = 0; ci < 2; ++ci)
        acc[ri][ci] = __builtin_amdgcn_mfma_f32_16x16x32_bf16(af[ri], bfr[ci], acc[ri][ci], 0, 0, 0);
  }

#pragma unroll
  for (int ri = 0; ri < 2; ++ri)
#pragma unroll
    for (int ci = 0; ci < 2; ++ci) {
      const int col = n0 + wn + ci * 16 + lo;
      const float bv = bias[col];
#pragma unroll
      for (int rr = 0; rr < 4; ++rr) {
        const int row = m0 + wm + ri * 16 + hi * 4 + rr;
        __builtin_nontemporal_store(acc[ri][ci][rr] + bv, &Op[row * Ntot + col]);
      }
    }
}

// ---------------------------------------------------------------- fused prep
// r22: x-conv range REMOVED (QKV GEMM now converts in staging). Ranges:
//   [0, 54)      conv8 qkv_w -> qkv_wb
//   [54, 72)     conv8 proj_w -> proj_wb
//   [72, 1096)   maskT (LDS-tiled 64x64 transpose, x log2e, bf16)
//   [1096, 2538) cpb1 (one wave per (r,h), shfl_xor reduce)
__global__ __launch_bounds__(256) void k_prep(
    const float* __restrict__ qkv_w, bf16* __restrict__ qkv_wb,
    const float* __restrict__ proj_w, bf16* __restrict__ proj_wb,
    const float* __restrict__ mask, bf16* __restrict__ maskT,
    const float* __restrict__ ct, const float* __restrict__ w1,
    const float* __restrict__ b1, const float* __restrict__ w2,
    float* __restrict__ bt) {
  __shared__ float tile[64][65];
  const int bid = blockIdx.x;
  if (bid < 72) {
    const float* in;
    bf16* o;
    int vb;
    if (bid < 54) { in = qkv_w; o = qkv_wb; vb = bid; }
    else { in = proj_w; o = proj_wb; vb = bid - 54; }
    const int i = (vb * 256 + threadIdx.x) * 8;
    const f32x4 a = *reinterpret_cast<const f32x4*>(&in[i]);
    const f32x4 b = *reinterpret_cast<const f32x4*>(&in[i + 4]);
    bf16x8 v;
    v[0] = (bf16)a[0]; v[1] = (bf16)a[1]; v[2] = (bf16)a[2]; v[3] = (bf16)a[3];
    v[4] = (bf16)b[0]; v[5] = (bf16)b[1]; v[6] = (bf16)b[2]; v[7] = (bf16)b[3];
    *reinterpret_cast<bf16x8*>(&o[i]) = v;
  } else if (bid < 1096) {
    const int rem = bid - 72;
    const int mb = rem >> 4;
    const int it = (rem & 15) >> 2, jt = rem & 3;
    const int tx = threadIdx.x & 63, ty = threadIdx.x >> 6;
    const float* mp = mask + mb * 65536;
#pragma unroll
    for (int rr = 0; rr < 16; ++rr)
      tile[rr * 4 + ty][tx] = mp[(it * 64 + rr * 4 + ty) * 256 + jt * 64 + tx];
    __syncthreads();
    bf16* op = maskT + mb * 65536;
#pragma unroll
    for (int rr = 0; rr < 16; ++rr)
      op[(jt * 64 + rr * 4 + ty) * 256 + it * 64 + tx] = (bf16)(LOG2E * tile[tx][rr * 4 + ty]);
  } else {
    // cpb1: bt[r][h] = (relu(ct[r] @ w1^T + b1) @ w2^T)[h], one wave per out
    const int wid = (bid - 1096) * 4 + (threadIdx.x >> 6);
    if (wid < 5766) {
      const int r = wid / 6, hh = wid % 6;
      const int lane = threadIdx.x & 63;
      const float t0 = ct[r * 2], t1 = ct[r * 2 + 1];
      float acc = 0.f;
#pragma unroll
      for (int jj = 0; jj < 8; ++jj) {
        const int j = lane + jj * 64;
        float hv = fmaf(w1[j * 2], t0, fmaf(w1[j * 2 + 1], t1, b1[j]));
        hv = fmaxf(hv, 0.f);
        acc = fmaf(hv, w2[hh * 512 + j], acc);
      }
      acc += __shfl_xor(acc, 1);
      acc += __shfl_xor(acc, 2);
      acc += __shfl_xor(acc, 4);
      acc += __shfl_xor(acc, 8);
      acc += __shfl_xor(acc, 16);
      acc += __shfl_xor(acc, 32);
      if (lane == 0) bt[wid] = acc;
    }
  }
}

// ---------------------------------------------------------------- attention
// r17 version verbatim (best attn: 105.8us, VGPR 128, cross-phase addend
// prefetch, f32 bias, raw v_exp_f32 exp2). FROZEN — 11 variants tried;
// distributed-latency-bound. Do not retry staging-duplicating splits (r20)
// or packed-b32 V staging (r13).
__global__ __launch_bounds__(256) void k_attn(const bf16* __restrict__ qkv,
                                              const bf16* __restrict__ maskT,
                                              const float* __restrict__ biasfT,
                                              bf16* __restrict__ aout) {
  __shared__ bf16 ksh[256 * 32];   // 16 KB
  __shared__ bf16 vts[32 * 256];   // 16 KB
  __shared__ bf16 ps[4 * 16 * 64]; //  8 KB

  // ---- XCD-aware remap (bijective): bid -> (b, h)
  const int bid = blockIdx.x;
  const int x = bid & 7, i = bid >> 3;       // i in [0,192)
  const int mb = x * 8 + i / 24;             // 8 masks per XCD
  const int rem = i % 24;
  const int b = (rem / 6) * 64 + mb;         // b & 63 == mb
  const int h = rem % 6;
  const int t = threadIdx.x;

  // ---- staging (k, v): rows t>>2 (+p*64), 16B chunk t&3
  const int rsub = t >> 2;
  const int c4s = t & 3;
#pragma unroll
  for (int p = 0; p < 4; ++p) {
    const int row = p * 64 + rsub;
    const int base = (b * 256 + row) * 576 + h * 32 + c4s * 8;
    *reinterpret_cast<bf16x8*>(&ksh[qk_idx(row, c4s * 8)]) =
        *reinterpret_cast<const bf16x8*>(&qkv[base + 192]);
    bf16x8 v = *reinterpret_cast<const bf16x8*>(&qkv[base + 384]);
#pragma unroll
    for (int jj = 0; jj < 8; ++jj) vts[vt_idx(c4s * 8 + jj, row)] = v[jj];
  }
  __syncthreads();

  const int w = t >> 6, lane = t & 63, lo = lane & 15, hi = lane >> 4;
  const float* bT = biasfT + (h << 16);
  const bf16* mT = maskT + (mb << 16);
  const bf16* qbase = qkv + (b * 256) * 576 + h * 32;

  // prefetch q fragment for the wave's first row group
  bf16x8 afn = *reinterpret_cast<const bf16x8*>(&qbase[(w * 16 + lo) * 576 + hi * 8]);

  // addend prefetch for rgi=0, ph=0
  f32x4 bvp[4];
  bf16x4 mvp[4];
  {
    const int rbase0 = w * 16 + hi * 4;
#pragma unroll
    for (int c = 0; c < 4; ++c) {
      const int col = c * 16 + lo;
      bvp[c] = *reinterpret_cast<const f32x4*>(&bT[col * 256 + rbase0]);
      mvp[c] = *reinterpret_cast<const bf16x4*>(&mT[col * 256 + rbase0]);
    }
  }

  for (int rgi = 0; rgi < 4; ++rgi) {
    const int rg = rgi * 4 + w;  // this wave's 16-row group; private -> no barriers
    const int rbase = rg * 16 + hi * 4;
    const bf16x8 af = afn;
    if (rgi < 3)  // issue next q load early (off the critical path)
      afn = *reinterpret_cast<const bf16x8*>(&qbase[((rg + 4) * 16 + lo) * 576 + hi * 8]);

    f32x4 po0 = {0.f, 0.f, 0.f, 0.f}, po1 = {0.f, 0.f, 0.f, 0.f};
    float sum[4] = {0.f, 0.f, 0.f, 0.f};

#pragma unroll
    for (int ph = 0; ph < 4; ++ph) {
      // ---- consume this phase's prefetched addends
      f32x4 bv[4];
      bf16x4 mv[4];
#pragma unroll
      for (int c = 0; c < 4; ++c) { bv[c] = bvp[c]; mv[c] = mvp[c]; }
      // ---- issue NEXT phase's addend loads (hidden under MFMA+exp below)
      if (ph < 3) {
#pragma unroll
        for (int c = 0; c < 4; ++c) {
          const int col = (ph + 1) * 64 + c * 16 + lo;
          bvp[c] = *reinterpret_cast<const f32x4*>(&bT[col * 256 + rbase]);
          mvp[c] = *reinterpret_cast<const bf16x4*>(&mT[col * 256 + rbase]);
        }
      } else if (rgi < 3) {  // first phase of the next row group (rbase+64)
#pragma unroll
        for (int c = 0; c < 4; ++c) {
          const int col = c * 16 + lo;
          bvp[c] = *reinterpret_cast<const f32x4*>(&bT[col * 256 + rbase + 64]);
          mvp[c] = *reinterpret_cast<const bf16x4*>(&mT[col * 256 + rbase + 64]);
        }
      }
      // ---- k fragments + S MFMAs
      bf16x8 kf[4];
#pragma unroll
      for (int c4i = 0; c4i < 4; ++c4i) {
        const int ct = ph * 4 + c4i;
        kf[c4i] = *reinterpret_cast<const bf16x8*>(&ksh[qk_idx(ct * 16 + lo, hi * 8)]);
      }
      f32x4 a[4];
#pragma unroll
      for (int c4i = 0; c4i < 4; ++c4i) {
        f32x4 z = {0.f, 0.f, 0.f, 0.f};
        a[c4i] = __builtin_amdgcn_mfma_f32_16x16x32_bf16(af, kf[c4i], z, 0, 0, 0);
      }
      // ---- fused addend+exp2+sum+p-store (unnormalized; raw v_exp_f32)
#pragma unroll
      for (int c4i = 0; c4i < 4; ++c4i)
#pragma unroll
        for (int rr = 0; rr < 4; ++rr) {
          const float s = a[c4i][rr] + bv[c4i][rr] + (float)mv[c4i][rr];
          const float p = __builtin_amdgcn_exp2f(s);
          sum[rr] += p;
          ps[p_idx4(w, hi * 4 + rr, c4i * 16 + lo)] = (bf16)p;
        }
      // ---- PV quarter (same-wave LDS producer/consumer; no barrier)
#pragma unroll
      for (int kb = 0; kb < 2; ++kb) {
        const bf16x8 pa = *reinterpret_cast<const bf16x8*>(&ps[p_idx4(w, lo, kb * 32 + hi * 8)]);
        const bf16x8 b0 = *reinterpret_cast<const bf16x8*>(&vts[vt_idx(lo, ph * 64 + kb * 32 + hi * 8)]);
        const bf16x8 b1 = *reinterpret_cast<const bf16x8*>(&vts[vt_idx(16 + lo, ph * 64 + kb * 32 + hi * 8)]);
        po0 = __builtin_amdgcn_mfma_f32_16x16x32_bf16(pa, b0, po0, 0, 0, 0);
        po1 = __builtin_amdgcn_mfma_f32_16x16x32_bf16(pa, b1, po1, 0, 0, 0);
      }
    }
    // ---- row-sum reduce across the 16 col-lanes, then normalize po
#pragma unroll
    for (int rr = 0; rr < 4; ++rr) {
      float s = sum[rr];
      s += __shfl_xor(s, 1, 16);
      s += __shfl_xor(s, 2, 16);
      s += __shfl_xor(s, 4, 16);
      s += __shfl_xor(s, 8, 16);
      sum[rr] = 1.f / s;
    }
    // ---- write attn-out (b, n, h*32+d) bf16
#pragma unroll
    for (int rr = 0; rr < 4; ++rr) {
      const int ob = (b * 256 + rbase + rr) * 192 + h * 32;
      aout[ob + lo] = (bf16)(po0[rr] * sum[rr]);
      aout[ob + 16 + lo] = (bf16)(po1[rr] * sum[rr]);
    }
  }
}

// ---------------------------------------------------------------- launcher
extern "C" void kernel_launch(void* const* d_in, const int* in_sizes, int n_in,
                              void* d_out, int out_size, void* d_ws, size_t ws_size,
                              hipStream_t stream) {
  const float* x      = (const float*)d_in[0];
  const float* mask   = (const float*)d_in[1];
  const float* qkv_w  = (const float*)d_in[2];
  const float* qkv_b  = (const float*)d_in[3];
  const float* proj_w = (const float*)d_in[4];
  const float* proj_b = (const float*)d_in[5];
  const float* lsc    = (const float*)d_in[6];
  const float* cpb_w1 = (const float*)d_in[7];
  const float* cpb_b1 = (const float*)d_in[8];
  const float* cpb_w2 = (const float*)d_in[9];
  const float* ctab   = (const float*)d_in[10];
  const int*   relidx = (const int*)d_in[11];

  char* ws = (char*)d_ws;
  bf16*  qkvb   = (bf16*)(ws);                      // 65536*576*2 = 75,497,472
  bf16*  aoutb  = (bf16*)(ws + 75497472);           // 65536*192*2 = 25,165,824
  float* biasfT = (float*)(ws + 100663296);         // 6*65536*4   =  1,572,864  (transposed, x log2e)
  bf16*  maskTb = (bf16*)(ws + 102236160);          // 64*65536*2  =  8,388,608  (transposed, x log2e)
  float* bt     = (float*)(ws + 110624768);         // 961*6*4     =     23,064
  bf16*  qkv_wb = (bf16*)(ws + 110647840);          // 576*192*2   =    221,184
  bf16*  proj_wb= (bf16*)(ws + 110869024);          // 192*192*2   =     73,728

  k_prep<<<2538, 256, 0, stream>>>(qkv_w, qkv_wb, proj_w, proj_wb,
                                   mask, maskTb, ctab, cpb_w1, cpb_b1, cpb_w2, bt);
  k_qkv<<<10752, 256, 0, stream>>>(x, qkv_wb, qkv_b, lsc, qkvb, bt, relidx, biasfT);
  k_attn<<<1536, 256, 0, stream>>>(qkvb, maskTb, biasfT, aoutb);
  k_gemm<3><<<3072, 256, 0, stream>>>(aoutb, proj_wb, proj_b, (float*)d_out, 192);
}